// Round 6
// baseline (283.345 us; speedup 1.0000x reference)
//
#include <hip/hip_runtime.h>

#define NR 1024        // num rois
#define NFG 80         // fg classes
#define CC 81          // total classes
#define KDIM 2048
#define H1DIM 256
#define H3DIM 512
#define D4 324         // 4*81

// ---------------- fused GEMM: H1 = relu(X@w1+b1), H3 = relu(X@w3+b3) --------
__global__ __launch_bounds__(256) void gemm2_relu_kernel(
    const float* __restrict__ A,
    const float* __restrict__ B1, const float* __restrict__ bias1, float* __restrict__ C1,
    const float* __restrict__ B2, const float* __restrict__ bias2, float* __restrict__ C2)
{
    const int bxb = blockIdx.x;
    const float* B; const float* bias; float* Cout; int Ncols; int col0;
    if (bxb < 4) { B = B1; bias = bias1; Cout = C1; Ncols = H1DIM; col0 = bxb * 64; }
    else         { B = B2; bias = bias2; Cout = C2; Ncols = H3DIM; col0 = (bxb - 4) * 64; }

    __shared__ float As[32][64];   // [k][m]
    __shared__ float Bs[32][64];   // [k][n]
    const int tid = threadIdx.x;
    const int tx = tid & 15;
    const int ty = tid >> 4;
    const int row0 = blockIdx.y * 64;

    const int la_r = tid >> 2;         // 0..63
    const int la_k = (tid & 3) * 4;    // 0,4,8,12
    const int lb_k = tid >> 4;         // 0..15
    const int lb_n = (tid & 15) * 4;   // 0..60

    float acc[4][4] = {};

    for (int k0 = 0; k0 < KDIM; k0 += 32) {
        float4 av0 = *reinterpret_cast<const float4*>(&A[(row0 + la_r) * KDIM + k0 + la_k]);
        float4 av1 = *reinterpret_cast<const float4*>(&A[(row0 + la_r) * KDIM + k0 + 16 + la_k]);
        float4 bv0 = *reinterpret_cast<const float4*>(&B[(k0 + lb_k) * Ncols + col0 + lb_n]);
        float4 bv1 = *reinterpret_cast<const float4*>(&B[(k0 + 16 + lb_k) * Ncols + col0 + lb_n]);
        __syncthreads();
        As[la_k + 0][la_r] = av0.x;
        As[la_k + 1][la_r] = av0.y;
        As[la_k + 2][la_r] = av0.z;
        As[la_k + 3][la_r] = av0.w;
        As[la_k + 16][la_r] = av1.x;
        As[la_k + 17][la_r] = av1.y;
        As[la_k + 18][la_r] = av1.z;
        As[la_k + 19][la_r] = av1.w;
        *reinterpret_cast<float4*>(&Bs[lb_k][lb_n])      = bv0;
        *reinterpret_cast<float4*>(&Bs[lb_k + 16][lb_n]) = bv1;
        __syncthreads();
#pragma unroll
        for (int kk = 0; kk < 32; kk++) {
            float4 a4 = *reinterpret_cast<const float4*>(&As[kk][ty * 4]);
            float4 b4 = *reinterpret_cast<const float4*>(&Bs[kk][tx * 4]);
            float a[4] = {a4.x, a4.y, a4.z, a4.w};
            float b[4] = {b4.x, b4.y, b4.z, b4.w};
#pragma unroll
            for (int i = 0; i < 4; i++)
#pragma unroll
                for (int j = 0; j < 4; j++)
                    acc[i][j] += a[i] * b[j];
        }
    }
#pragma unroll
    for (int i = 0; i < 4; i++) {
        int row = row0 + ty * 4 + i;
#pragma unroll
        for (int j = 0; j < 4; j++) {
            int col = col0 + tx * 4 + j;
            float v = acc[i][j] + bias[col];
            Cout[row * Ncols + col] = v > 0.f ? v : 0.f;
        }
    }
}

// ---------------- fused per-ROI postproc: softmax + bbox decode, 8 ROIs/block ----------------
// wave ri (of 8) computes roi ri's logits+softmax fully in-register (shuffle reduce);
// threads t<324 compute the delta matvec for all 8 rois at once (w4 read once, broadcast h3).
__global__ __launch_bounds__(512) void postproc_kernel(
    const float* __restrict__ H1, const float* __restrict__ w2, const float* __restrict__ b2,
    const float* __restrict__ H3, const float* __restrict__ w4, const float* __restrict__ b4,
    const float* __restrict__ rois, const float* __restrict__ im_info,
    float* __restrict__ probs, float* __restrict__ boxes)
{
    const int r0 = blockIdx.x * 8;
    const int t = threadIdx.x;
    __shared__ float h1s[H1DIM][8];
    __shared__ float h3s[H3DIM][8];
    __shared__ float dl[8][D4];

#pragma unroll
    for (int rep = 0; rep < 4; rep++) {
        int idx = t + rep * 512;          // 0..2047
        int ri = idx >> 8, k = idx & 255;
        h1s[k][ri] = H1[(r0 + ri) * H1DIM + k];
    }
#pragma unroll
    for (int rep = 0; rep < 8; rep++) {
        int idx = t + rep * 512;          // 0..4095
        int ri = idx >> 9, k = idx & 511;
        h3s[k][ri] = H3[(r0 + ri) * H3DIM + k];
    }
    __syncthreads();

    // deltas: thread d (<324) does the full 512-dot for all 8 rois
    if (t < D4) {
        float acc[8] = {};
        for (int k = 0; k < H3DIM; k++) {
            float w = w4[k * D4 + t];
            float4 a = *reinterpret_cast<const float4*>(&h3s[k][0]);
            float4 b = *reinterpret_cast<const float4*>(&h3s[k][4]);
            acc[0] += a.x * w; acc[1] += a.y * w; acc[2] += a.z * w; acc[3] += a.w * w;
            acc[4] += b.x * w; acc[5] += b.y * w; acc[6] += b.z * w; acc[7] += b.w * w;
        }
        const float stdv = ((t & 3) < 2) ? 0.1f : 0.2f;
#pragma unroll
        for (int ri = 0; ri < 8; ri++) dl[ri][t] = (acc[ri] + b4[t]) * stdv;
    }

    // logits + softmax: wave ri handles roi ri, lane l handles classes l and l+64
    {
        const int ri = t >> 6, l = t & 63;
        const bool hi = (l + 64 < CC);
        float acc0 = 0.f, acc1 = 0.f;
        for (int k = 0; k < H1DIM; k++) {
            float h = h1s[k][ri];
            acc0 += h * w2[k * CC + l];
            if (hi) acc1 += h * w2[k * CC + l + 64];
        }
        acc0 += b2[l];
        if (hi) acc1 += b2[l + 64];
        float m = fmaxf(acc0, hi ? acc1 : -1e30f);
#pragma unroll
        for (int off = 32; off; off >>= 1) m = fmaxf(m, __shfl_xor(m, off, 64));
        float e0 = expf(acc0 - m);
        float e1 = hi ? expf(acc1 - m) : 0.f;
        float s = e0 + e1;
#pragma unroll
        for (int off = 32; off; off >>= 1) s += __shfl_xor(s, off, 64);
        if (l >= 1) probs[(l - 1) * NR + (r0 + ri)] = e0 / s;
        if (hi)     probs[(l + 63) * NR + (r0 + ri)] = e1 / s;
    }
    __syncthreads();

    // decode: 640 tasks = 8 rois x 80 fg classes
    for (int u = t; u < 640; u += 512) {
        const int ri = u & 7, cf = u >> 3;
        const int cls = cf + 1;
        const int r = r0 + ri;
        float x1 = rois[r * 5 + 1], y1 = rois[r * 5 + 2];
        float x2 = rois[r * 5 + 3], y2 = rois[r * 5 + 4];
        float wdt = x2 - x1 + 1.f, hgt = y2 - y1 + 1.f;
        float ctx = x1 + 0.5f * wdt, cty = y1 + 0.5f * hgt;
        float dx = dl[ri][cls * 4 + 0], dy = dl[ri][cls * 4 + 1];
        float dw = dl[ri][cls * 4 + 2], dh = dl[ri][cls * 4 + 3];
        float pcx = dx * wdt + ctx, pcy = dy * hgt + cty;
        float pw = expf(dw) * wdt, ph = expf(dh) * hgt;
        float Hm1 = im_info[0] - 1.f, Wm1 = im_info[1] - 1.f;
        float inv = 1.f / im_info[2];
        float b0 = fminf(fmaxf(pcx - 0.5f * pw, 0.f), Wm1) * inv;
        float b1 = fminf(fmaxf(pcy - 0.5f * ph, 0.f), Hm1) * inv;
        float b2v = fminf(fmaxf(pcx + 0.5f * pw, 0.f), Wm1) * inv;
        float b3v = fminf(fmaxf(pcy + 0.5f * ph, 0.f), Hm1) * inv;
        float* bp = &boxes[(cf * NR + r) * 4];
        bp[0] = b0; bp[1] = b1; bp[2] = b2v; bp[3] = b3v;
    }
}

// ---------------- per-class: compact -> rank-sort -> ballot NMS -> kept-iteration scan ------
__global__ __launch_bounds__(512) void sort_nms_kernel(
    const float* __restrict__ probs, const float* __restrict__ boxes,
    float* __restrict__ out)
{
    const int c = blockIdx.x;
    const int t = threadIdx.x;
    const int lane = t & 63;
    const int wave = t >> 6;       // 0..7

    __shared__ float cs_sc[NR];
    __shared__ int   cs_ix[NR];
    __shared__ float ss[NR];
    __shared__ int   sx[NR];
    __shared__ float bx[NR][4];
    __shared__ unsigned long long over_[256][4];   // symmetric overlap bits per chunk
    __shared__ unsigned long long presup_w[4];
    __shared__ unsigned long long keep_w[16];      // kept bitset over sorted positions
    __shared__ int vcount;

    if (t == 0) vcount = 0;
    if (t < 4) presup_w[t] = 0;
    if (t < 16) keep_w[t] = 0;
    __syncthreads();

    // compact valid entries (order nondeterministic; rank restores determinism)
    for (int i = t; i < NR; i += 512) {
        float s = probs[c * NR + i];
        if (s > 0.05f) {
            int p = atomicAdd(&vcount, 1);
            cs_sc[p] = s; cs_ix[p] = i;
        }
    }
    __syncthreads();
    const int V = vcount;

    // wave-parallel exact stable rank (score desc, idx asc)
    for (int e = wave; e < V; e += 8) {
        const float se = cs_sc[e];
        const int   ie = cs_ix[e];
        int cnt = 0;
        for (int f = lane; f < V; f += 64) {
            float sf = cs_sc[f];
            int   jf = cs_ix[f];
            if (sf > se || (sf == se && jf < ie)) cnt++;
        }
#pragma unroll
        for (int off = 32; off; off >>= 1) cnt += __shfl_xor(cnt, off, 64);
        if (lane == 0) { ss[cnt] = se; sx[cnt] = ie; }
    }
    __syncthreads();

    // gather boxes in sorted order
    for (int i = t; i < V; i += 512) {
        float4 b = *reinterpret_cast<const float4*>(&boxes[(c * NR + sx[i]) * 4]);
        bx[i][0] = b.x; bx[i][1] = b.y; bx[i][2] = b.z; bx[i][3] = b.w;
    }
    __syncthreads();

    // chunked NMS
    for (int cs = 0; cs < V; cs += 256) {
        const int n = min(256, V - cs);

        for (int i = wave; i < n; i += 8) {
            const int gi = cs + i;
            const float x1i = bx[gi][0], y1i = bx[gi][1], x2i = bx[gi][2], y2i = bx[gi][3];
            const float ai = (x2i - x1i + 1.f) * (y2i - y1i + 1.f);

            // cross-chunk presup vs kept of earlier chunks
            if (cs > 0) {
                int sup = 0;
                for (int j = lane; j < cs; j += 64) {
                    if ((keep_w[j >> 6] >> (j & 63)) & 1ULL) {
                        float iw = fminf(x2i, bx[j][2]) - fmaxf(x1i, bx[j][0]) + 1.f;
                        float ih = fminf(y2i, bx[j][3]) - fmaxf(y1i, bx[j][1]) + 1.f;
                        if (iw > 0.f && ih > 0.f) {
                            float inter = iw * ih;
                            float aj = (bx[j][2] - bx[j][0] + 1.f) * (bx[j][3] - bx[j][1] + 1.f);
                            if (inter / (ai + aj - inter) > 0.3f) sup = 1;
                        }
                    }
                }
                int anysup = __any(sup);
                if (anysup && lane == 0)
                    atomicOr(&presup_w[i >> 6], 1ULL << (i & 63));
            }

            // symmetric intra-chunk overlap bits (self bit included)
#pragma unroll
            for (int w = 0; w < 4; w++) {
                int jj = w * 64 + lane;
                int pred = 0;
                if (jj < n) {
                    const int gj = cs + jj;
                    float iw = fminf(x2i, bx[gj][2]) - fmaxf(x1i, bx[gj][0]) + 1.f;
                    float ih = fminf(y2i, bx[gj][3]) - fmaxf(y1i, bx[gj][1]) + 1.f;
                    if (iw > 0.f && ih > 0.f) {
                        float inter = iw * ih;
                        float aj = (bx[gj][2] - bx[gj][0] + 1.f) * (bx[gj][3] - bx[gj][1] + 1.f);
                        if (inter / (ai + aj - inter) > 0.3f) pred = 1;
                    }
                }
                unsigned long long bits = __ballot(pred);
                if (lane == 0) over_[i][w] = bits;
            }
        }
        __syncthreads();

        // greedy scan over KEPT boxes only (~#kept iterations, not n)
        if (t == 0) {
            unsigned long long alive[4], kept[4] = {0ULL, 0ULL, 0ULL, 0ULL};
#pragma unroll
            for (int w = 0; w < 4; w++) {
                int rem = n - w * 64;
                unsigned long long cand =
                    rem >= 64 ? ~0ULL : (rem > 0 ? ((1ULL << rem) - 1ULL) : 0ULL);
                alive[w] = cand & ~presup_w[w];
            }
            while (true) {
                int w = 0;
                while (w < 4 && alive[w] == 0ULL) w++;
                if (w == 4) break;
                int b = __builtin_ctzll(alive[w]);
                int i = w * 64 + b;
                kept[w] |= (1ULL << b);
                alive[0] &= ~over_[i][0]; alive[1] &= ~over_[i][1];
                alive[2] &= ~over_[i][2]; alive[3] &= ~over_[i][3];
                alive[w] &= ~(1ULL << b);
            }
#pragma unroll
            for (int w = 0; w < 4; w++) {
                keep_w[(cs >> 6) + w] = kept[w];
                presup_w[w] = 0ULL;   // reset for next chunk
            }
        }
        __syncthreads();
    }

    // emit dets[c][i][6]
    for (int i = t; i < NR; i += 512) {
        float2* o = reinterpret_cast<float2*>(&out[(size_t)(c * NR + i) * 6]);
        bool kp = (i < V) && ((keep_w[i >> 6] >> (i & 63)) & 1ULL);
        float2 p0, p1, p2;
        if (kp) {
            p0 = make_float2(bx[i][0], bx[i][1]);
            p1 = make_float2(bx[i][2], bx[i][3]);
            p2 = make_float2(ss[i], (float)c);
        } else {
            p0 = make_float2(0.f, 0.f);
            p1 = make_float2(0.f, 0.f);
            p2 = make_float2(0.f, 0.f);
        }
        o[0] = p0; o[1] = p1; o[2] = p2;
    }
}

extern "C" void kernel_launch(void* const* d_in, const int* in_sizes, int n_in,
                              void* d_out, int out_size, void* d_ws, size_t ws_size,
                              hipStream_t stream)
{
    const float* X    = (const float*)d_in[0];
    const float* rois = (const float*)d_in[1];
    const float* imi  = (const float*)d_in[2];
    const float* w1   = (const float*)d_in[3];
    const float* b1   = (const float*)d_in[4];
    const float* w2   = (const float*)d_in[5];
    const float* b2   = (const float*)d_in[6];
    const float* w3   = (const float*)d_in[7];
    const float* b3   = (const float*)d_in[8];
    const float* w4   = (const float*)d_in[9];
    const float* b4   = (const float*)d_in[10];
    float* out = (float*)d_out;

    float* ws    = (float*)d_ws;
    float* H1    = ws;                       // 1024*256
    float* H3    = H1 + NR * H1DIM;          // 1024*512
    float* probs = H3 + NR * H3DIM;          // 80*1024
    float* boxes = probs + NFG * NR;         // 80*1024*4

    gemm2_relu_kernel<<<dim3(12, NR / 64), 256, 0, stream>>>(X, w1, b1, H1, w3, b3, H3);
    postproc_kernel<<<NR / 8, 512, 0, stream>>>(H1, w2, b2, H3, w4, b4, rois, imi, probs, boxes);
    sort_nms_kernel<<<NFG, 512, 0, stream>>>(probs, boxes, out);
}

// Round 7
// 244.590 us; speedup vs baseline: 1.1584x; 1.1584x over previous
//
#include <hip/hip_runtime.h>

#define NR 1024        // num rois
#define NFG 80         // fg classes
#define CC 81          // total classes
#define KDIM 2048
#define H1DIM 256
#define H3DIM 512
#define D4 324         // 4*81

// ---------------- fused GEMM: H1 = relu(X@w1+b1), H3 = relu(X@w3+b3) --------
__global__ __launch_bounds__(256) void gemm2_relu_kernel(
    const float* __restrict__ A,
    const float* __restrict__ B1, const float* __restrict__ bias1, float* __restrict__ C1,
    const float* __restrict__ B2, const float* __restrict__ bias2, float* __restrict__ C2)
{
    const int bxb = blockIdx.x;
    const float* B; const float* bias; float* Cout; int Ncols; int col0;
    if (bxb < 4) { B = B1; bias = bias1; Cout = C1; Ncols = H1DIM; col0 = bxb * 64; }
    else         { B = B2; bias = bias2; Cout = C2; Ncols = H3DIM; col0 = (bxb - 4) * 64; }

    __shared__ float As[32][64];   // [k][m]
    __shared__ float Bs[32][64];   // [k][n]
    const int tid = threadIdx.x;
    const int tx = tid & 15;
    const int ty = tid >> 4;
    const int row0 = blockIdx.y * 64;

    const int la_r = tid >> 2;         // 0..63
    const int la_k = (tid & 3) * 4;    // 0,4,8,12
    const int lb_k = tid >> 4;         // 0..15
    const int lb_n = (tid & 15) * 4;   // 0..60

    float acc[4][4] = {};

    for (int k0 = 0; k0 < KDIM; k0 += 32) {
        float4 av0 = *reinterpret_cast<const float4*>(&A[(row0 + la_r) * KDIM + k0 + la_k]);
        float4 av1 = *reinterpret_cast<const float4*>(&A[(row0 + la_r) * KDIM + k0 + 16 + la_k]);
        float4 bv0 = *reinterpret_cast<const float4*>(&B[(k0 + lb_k) * Ncols + col0 + lb_n]);
        float4 bv1 = *reinterpret_cast<const float4*>(&B[(k0 + 16 + lb_k) * Ncols + col0 + lb_n]);
        __syncthreads();
        As[la_k + 0][la_r] = av0.x;
        As[la_k + 1][la_r] = av0.y;
        As[la_k + 2][la_r] = av0.z;
        As[la_k + 3][la_r] = av0.w;
        As[la_k + 16][la_r] = av1.x;
        As[la_k + 17][la_r] = av1.y;
        As[la_k + 18][la_r] = av1.z;
        As[la_k + 19][la_r] = av1.w;
        *reinterpret_cast<float4*>(&Bs[lb_k][lb_n])      = bv0;
        *reinterpret_cast<float4*>(&Bs[lb_k + 16][lb_n]) = bv1;
        __syncthreads();
#pragma unroll
        for (int kk = 0; kk < 32; kk++) {
            float4 a4 = *reinterpret_cast<const float4*>(&As[kk][ty * 4]);
            float4 b4 = *reinterpret_cast<const float4*>(&Bs[kk][tx * 4]);
            float a[4] = {a4.x, a4.y, a4.z, a4.w};
            float b[4] = {b4.x, b4.y, b4.z, b4.w};
#pragma unroll
            for (int i = 0; i < 4; i++)
#pragma unroll
                for (int j = 0; j < 4; j++)
                    acc[i][j] += a[i] * b[j];
        }
    }
#pragma unroll
    for (int i = 0; i < 4; i++) {
        int row = row0 + ty * 4 + i;
#pragma unroll
        for (int j = 0; j < 4; j++) {
            int col = col0 + tx * 4 + j;
            float v = acc[i][j] + bias[col];
            Cout[row * Ncols + col] = v > 0.f ? v : 0.f;
        }
    }
}

// ---------------- scores: softmax(H1 @ w2 + b2), store fg probs class-major ----------------
__global__ __launch_bounds__(128) void scores_softmax_kernel(
    const float* __restrict__ H1, const float* __restrict__ w2,
    const float* __restrict__ b2, float* __restrict__ probs)
{
    const int r = blockIdx.x;
    const int t = threadIdx.x;
    __shared__ float h[H1DIM];
    __shared__ float lg[CC];
    __shared__ float red[128];

    h[t]       = H1[r * H1DIM + t];
    h[t + 128] = H1[r * H1DIM + t + 128];
    __syncthreads();

    if (t < CC) {
        float acc = b2[t];
        for (int k = 0; k < H1DIM; k++) acc += h[k] * w2[k * CC + t];
        lg[t] = acc;
    }
    __syncthreads();

    red[t] = (t < CC) ? lg[t] : -1e30f;
    __syncthreads();
    for (int s = 64; s > 0; s >>= 1) {
        if (t < s) red[t] = fmaxf(red[t], red[t + s]);
        __syncthreads();
    }
    float mx = red[0];
    __syncthreads();

    float e = 0.f;
    if (t < CC) e = expf(lg[t] - mx);
    red[t] = e;
    __syncthreads();
    for (int s = 64; s > 0; s >>= 1) {
        if (t < s) red[t] += red[t + s];
        __syncthreads();
    }
    float sum = red[0];

    if (t >= 1 && t < CC) probs[(t - 1) * NR + r] = e / sum;
}

// ---------------- per-class: compact -> rank-sort -> deltas(valid only)+decode -> NMS -> emit
// The w4 GEMM slice (4 columns of this class) is computed HERE, only for the V valid
// ROIs (wave per ROI, lanes split k, shuffle reduce). Phase-3 scan uses named registers
// (no runtime-indexed locals -> no scratch).
__global__ __launch_bounds__(512) void class_nms_kernel(
    const float* __restrict__ probs, const float* __restrict__ H3,
    const float* __restrict__ w4, const float* __restrict__ b4,
    const float* __restrict__ rois, const float* __restrict__ im_info,
    float* __restrict__ out)
{
    const int c = blockIdx.x;          // fg class 0..79 (real class c+1)
    const int t = threadIdx.x;
    const int lane = t & 63;
    const int wave = t >> 6;           // 0..7

    __shared__ float w4s[4][H3DIM];    // this class's 4 w4 columns, comp-major
    __shared__ float b4s[4];
    __shared__ float imv[3];
    __shared__ float cs_sc[NR];
    __shared__ int   cs_ix[NR];
    __shared__ float ss[NR];
    __shared__ int   sx[NR];
    __shared__ float bx[NR][4];
    __shared__ unsigned long long over_[256][4];
    __shared__ unsigned long long presup_w[4];
    __shared__ unsigned long long keep_w[16];
    __shared__ int vcount;

    // stage the w4 slice (columns (c+1)*4 .. +3), b4 slice, im_info
    for (int u = t; u < H3DIM * 4; u += 512) {
        int k = u >> 2, comp = u & 3;
        w4s[comp][k] = w4[k * D4 + (c + 1) * 4 + comp];
    }
    if (t < 4) { b4s[t] = b4[(c + 1) * 4 + t]; presup_w[t] = 0ULL; }
    if (t < 3) imv[t] = im_info[t];
    if (t < 16) keep_w[t] = 0ULL;
    if (t == 0) vcount = 0;
    __syncthreads();

    // compact valid entries (order nondeterministic; rank restores determinism)
    for (int i = t; i < NR; i += 512) {
        float s = probs[c * NR + i];
        if (s > 0.05f) {
            int p = atomicAdd(&vcount, 1);
            cs_sc[p] = s; cs_ix[p] = i;
        }
    }
    __syncthreads();
    const int V = vcount;

    // wave-parallel exact stable rank (score desc, idx asc)
    for (int e = wave; e < V; e += 8) {
        const float se = cs_sc[e];
        const int   ie = cs_ix[e];
        int cnt = 0;
        for (int f = lane; f < V; f += 64) {
            float sf = cs_sc[f];
            int   jf = cs_ix[f];
            if (sf > se || (sf == se && jf < ie)) cnt++;
        }
#pragma unroll
        for (int off = 32; off; off >>= 1) cnt += __shfl_xor(cnt, off, 64);
        if (lane == 0) { ss[cnt] = se; sx[cnt] = ie; }
    }
    __syncthreads();

    // deltas + decode for valid ROIs only: wave per sorted entry, lanes split k
    const float Hm1 = imv[0] - 1.f, Wm1 = imv[1] - 1.f, inv = 1.f / imv[2];
    for (int i = wave; i < V; i += 8) {
        const int r = sx[i];
        const float* h3r = &H3[r * H3DIM];
        float a0 = 0.f, a1 = 0.f, a2 = 0.f, a3 = 0.f;
#pragma unroll
        for (int j = 0; j < 8; j++) {
            int k = lane + j * 64;
            float h = h3r[k];
            a0 += h * w4s[0][k];
            a1 += h * w4s[1][k];
            a2 += h * w4s[2][k];
            a3 += h * w4s[3][k];
        }
#pragma unroll
        for (int off = 32; off; off >>= 1) {
            a0 += __shfl_xor(a0, off, 64);
            a1 += __shfl_xor(a1, off, 64);
            a2 += __shfl_xor(a2, off, 64);
            a3 += __shfl_xor(a3, off, 64);
        }
        if (lane == 0) {
            float dx = (a0 + b4s[0]) * 0.1f;
            float dy = (a1 + b4s[1]) * 0.1f;
            float dw = (a2 + b4s[2]) * 0.2f;
            float dh = (a3 + b4s[3]) * 0.2f;
            float x1 = rois[r * 5 + 1], y1 = rois[r * 5 + 2];
            float x2 = rois[r * 5 + 3], y2 = rois[r * 5 + 4];
            float wdt = x2 - x1 + 1.f, hgt = y2 - y1 + 1.f;
            float ctx = x1 + 0.5f * wdt, cty = y1 + 0.5f * hgt;
            float pcx = dx * wdt + ctx, pcy = dy * hgt + cty;
            float pw = expf(dw) * wdt, ph = expf(dh) * hgt;
            bx[i][0] = fminf(fmaxf(pcx - 0.5f * pw, 0.f), Wm1) * inv;
            bx[i][1] = fminf(fmaxf(pcy - 0.5f * ph, 0.f), Hm1) * inv;
            bx[i][2] = fminf(fmaxf(pcx + 0.5f * pw, 0.f), Wm1) * inv;
            bx[i][3] = fminf(fmaxf(pcy + 0.5f * ph, 0.f), Hm1) * inv;
        }
    }
    __syncthreads();

    // chunked NMS over sorted-valid entries
    for (int cs = 0; cs < V; cs += 256) {
        const int n = min(256, V - cs);

        for (int i = wave; i < n; i += 8) {
            const int gi = cs + i;
            const float x1i = bx[gi][0], y1i = bx[gi][1], x2i = bx[gi][2], y2i = bx[gi][3];
            const float ai = (x2i - x1i + 1.f) * (y2i - y1i + 1.f);

            // cross-chunk presup vs kept of earlier chunks
            if (cs > 0) {
                int sup = 0;
                for (int j = lane; j < cs; j += 64) {
                    if ((keep_w[j >> 6] >> (j & 63)) & 1ULL) {
                        float iw = fminf(x2i, bx[j][2]) - fmaxf(x1i, bx[j][0]) + 1.f;
                        float ih = fminf(y2i, bx[j][3]) - fmaxf(y1i, bx[j][1]) + 1.f;
                        if (iw > 0.f && ih > 0.f) {
                            float inter = iw * ih;
                            float aj = (bx[j][2] - bx[j][0] + 1.f) * (bx[j][3] - bx[j][1] + 1.f);
                            if (inter / (ai + aj - inter) > 0.3f) sup = 1;
                        }
                    }
                }
                int anysup = __any(sup);
                if (anysup && lane == 0)
                    atomicOr(&presup_w[i >> 6], 1ULL << (i & 63));
            }

            // symmetric intra-chunk overlap bits (self bit included)
#pragma unroll
            for (int w = 0; w < 4; w++) {
                int jj = w * 64 + lane;
                int pred = 0;
                if (jj < n) {
                    const int gj = cs + jj;
                    float iw = fminf(x2i, bx[gj][2]) - fmaxf(x1i, bx[gj][0]) + 1.f;
                    float ih = fminf(y2i, bx[gj][3]) - fmaxf(y1i, bx[gj][1]) + 1.f;
                    if (iw > 0.f && ih > 0.f) {
                        float inter = iw * ih;
                        float aj = (bx[gj][2] - bx[gj][0] + 1.f) * (bx[gj][3] - bx[gj][1] + 1.f);
                        if (inter / (ai + aj - inter) > 0.3f) pred = 1;
                    }
                }
                unsigned long long bits = __ballot(pred);
                if (lane == 0) over_[i][w] = bits;
            }
        }
        __syncthreads();

        // greedy scan over kept boxes only — named registers, all static indexing
        if (t == 0) {
            int rem0 = n, rem1 = n - 64, rem2 = n - 128, rem3 = n - 192;
            unsigned long long m0 = rem0 >= 64 ? ~0ULL : (rem0 > 0 ? ((1ULL << rem0) - 1) : 0ULL);
            unsigned long long m1 = rem1 >= 64 ? ~0ULL : (rem1 > 0 ? ((1ULL << rem1) - 1) : 0ULL);
            unsigned long long m2 = rem2 >= 64 ? ~0ULL : (rem2 > 0 ? ((1ULL << rem2) - 1) : 0ULL);
            unsigned long long m3 = rem3 >= 64 ? ~0ULL : (rem3 > 0 ? ((1ULL << rem3) - 1) : 0ULL);
            unsigned long long alive0 = m0 & ~presup_w[0];
            unsigned long long alive1 = m1 & ~presup_w[1];
            unsigned long long alive2 = m2 & ~presup_w[2];
            unsigned long long alive3 = m3 & ~presup_w[3];
            unsigned long long kept0 = 0, kept1 = 0, kept2 = 0, kept3 = 0;
            while (alive0 | alive1 | alive2 | alive3) {
                int i;
                if (alive0)      { int b = __builtin_ctzll(alive0); i = b;       kept0 |= 1ULL << b; }
                else if (alive1) { int b = __builtin_ctzll(alive1); i = 64 + b;  kept1 |= 1ULL << b; }
                else if (alive2) { int b = __builtin_ctzll(alive2); i = 128 + b; kept2 |= 1ULL << b; }
                else             { int b = __builtin_ctzll(alive3); i = 192 + b; kept3 |= 1ULL << b; }
                alive0 &= ~over_[i][0];   // self bit is set in over_ -> clears itself
                alive1 &= ~over_[i][1];
                alive2 &= ~over_[i][2];
                alive3 &= ~over_[i][3];
            }
            const int kwb = cs >> 6;
            keep_w[kwb + 0] = kept0; keep_w[kwb + 1] = kept1;
            keep_w[kwb + 2] = kept2; keep_w[kwb + 3] = kept3;
            presup_w[0] = presup_w[1] = presup_w[2] = presup_w[3] = 0ULL;
        }
        __syncthreads();
    }

    // emit dets[c][i][6]
    for (int i = t; i < NR; i += 512) {
        float2* o = reinterpret_cast<float2*>(&out[(size_t)(c * NR + i) * 6]);
        bool kp = (i < V) && ((keep_w[i >> 6] >> (i & 63)) & 1ULL);
        float2 p0, p1, p2;
        if (kp) {
            p0 = make_float2(bx[i][0], bx[i][1]);
            p1 = make_float2(bx[i][2], bx[i][3]);
            p2 = make_float2(ss[i], (float)c);
        } else {
            p0 = make_float2(0.f, 0.f);
            p1 = make_float2(0.f, 0.f);
            p2 = make_float2(0.f, 0.f);
        }
        o[0] = p0; o[1] = p1; o[2] = p2;
    }
}

extern "C" void kernel_launch(void* const* d_in, const int* in_sizes, int n_in,
                              void* d_out, int out_size, void* d_ws, size_t ws_size,
                              hipStream_t stream)
{
    const float* X    = (const float*)d_in[0];
    const float* rois = (const float*)d_in[1];
    const float* imi  = (const float*)d_in[2];
    const float* w1   = (const float*)d_in[3];
    const float* b1   = (const float*)d_in[4];
    const float* w2   = (const float*)d_in[5];
    const float* b2   = (const float*)d_in[6];
    const float* w3   = (const float*)d_in[7];
    const float* b3   = (const float*)d_in[8];
    const float* w4   = (const float*)d_in[9];
    const float* b4   = (const float*)d_in[10];
    float* out = (float*)d_out;

    float* ws    = (float*)d_ws;
    float* H1    = ws;                       // 1024*256
    float* H3    = H1 + NR * H1DIM;          // 1024*512
    float* probs = H3 + NR * H3DIM;          // 80*1024

    gemm2_relu_kernel<<<dim3(12, NR / 64), 256, 0, stream>>>(X, w1, b1, H1, w3, b3, H3);
    scores_softmax_kernel<<<NR, 128, 0, stream>>>(H1, w2, b2, probs);
    class_nms_kernel<<<NFG, 512, 0, stream>>>(probs, H3, w4, b4, rois, imi, out);
}

// Round 8
// 232.572 us; speedup vs baseline: 1.2183x; 1.0517x over previous
//
#include <hip/hip_runtime.h>

#define NR 1024        // num rois
#define NFG 80         // fg classes
#define CC 81          // total classes
#define KDIM 2048
#define H1DIM 256
#define H3DIM 512
#define D4 324         // 4*81

// ---------------- fused GEMM: H1 = relu(X@w1+b1), H3 = relu(X@w3+b3) --------
__global__ __launch_bounds__(256) void gemm2_relu_kernel(
    const float* __restrict__ A,
    const float* __restrict__ B1, const float* __restrict__ bias1, float* __restrict__ C1,
    const float* __restrict__ B2, const float* __restrict__ bias2, float* __restrict__ C2)
{
    const int bxb = blockIdx.x;
    const float* B; const float* bias; float* Cout; int Ncols; int col0;
    if (bxb < 4) { B = B1; bias = bias1; Cout = C1; Ncols = H1DIM; col0 = bxb * 64; }
    else         { B = B2; bias = bias2; Cout = C2; Ncols = H3DIM; col0 = (bxb - 4) * 64; }

    __shared__ float As[32][64];   // [k][m]
    __shared__ float Bs[32][64];   // [k][n]
    const int tid = threadIdx.x;
    const int tx = tid & 15;
    const int ty = tid >> 4;
    const int row0 = blockIdx.y * 64;

    const int la_r = tid >> 2;
    const int la_k = (tid & 3) * 4;
    const int lb_k = tid >> 4;
    const int lb_n = (tid & 15) * 4;

    float acc[4][4] = {};

    for (int k0 = 0; k0 < KDIM; k0 += 32) {
        float4 av0 = *reinterpret_cast<const float4*>(&A[(row0 + la_r) * KDIM + k0 + la_k]);
        float4 av1 = *reinterpret_cast<const float4*>(&A[(row0 + la_r) * KDIM + k0 + 16 + la_k]);
        float4 bv0 = *reinterpret_cast<const float4*>(&B[(k0 + lb_k) * Ncols + col0 + lb_n]);
        float4 bv1 = *reinterpret_cast<const float4*>(&B[(k0 + 16 + lb_k) * Ncols + col0 + lb_n]);
        __syncthreads();
        As[la_k + 0][la_r] = av0.x;
        As[la_k + 1][la_r] = av0.y;
        As[la_k + 2][la_r] = av0.z;
        As[la_k + 3][la_r] = av0.w;
        As[la_k + 16][la_r] = av1.x;
        As[la_k + 17][la_r] = av1.y;
        As[la_k + 18][la_r] = av1.z;
        As[la_k + 19][la_r] = av1.w;
        *reinterpret_cast<float4*>(&Bs[lb_k][lb_n])      = bv0;
        *reinterpret_cast<float4*>(&Bs[lb_k + 16][lb_n]) = bv1;
        __syncthreads();
#pragma unroll
        for (int kk = 0; kk < 32; kk++) {
            float4 a4 = *reinterpret_cast<const float4*>(&As[kk][ty * 4]);
            float4 b4 = *reinterpret_cast<const float4*>(&Bs[kk][tx * 4]);
            float a[4] = {a4.x, a4.y, a4.z, a4.w};
            float b[4] = {b4.x, b4.y, b4.z, b4.w};
#pragma unroll
            for (int i = 0; i < 4; i++)
#pragma unroll
                for (int j = 0; j < 4; j++)
                    acc[i][j] += a[i] * b[j];
        }
    }
#pragma unroll
    for (int i = 0; i < 4; i++) {
        int row = row0 + ty * 4 + i;
#pragma unroll
        for (int j = 0; j < 4; j++) {
            int col = col0 + tx * 4 + j;
            float v = acc[i][j] + bias[col];
            Cout[row * Ncols + col] = v > 0.f ? v : 0.f;
        }
    }
}

// ---------------- deltas GEMM: D = H3 @ w4 + b4 (raw, no relu), N=324 guarded ----------------
__global__ __launch_bounds__(256) void gemm_deltas_kernel(
    const float* __restrict__ A, const float* __restrict__ B,
    const float* __restrict__ bias, float* __restrict__ D)
{
    __shared__ float As[32][64];
    __shared__ float Bs[32][64];
    const int tid = threadIdx.x;
    const int tx = tid & 15;
    const int ty = tid >> 4;
    const int row0 = blockIdx.y * 64;
    const int col0 = blockIdx.x * 64;

    const int la_r = tid >> 2;
    const int la_k = (tid & 3) * 4;
    const int lb_k = tid >> 4;
    const int lb_n = (tid & 15) * 4;
    const bool full = (col0 + 64 <= D4);

    float acc[4][4] = {};

    for (int k0 = 0; k0 < H3DIM; k0 += 32) {
        float4 av0 = *reinterpret_cast<const float4*>(&A[(row0 + la_r) * H3DIM + k0 + la_k]);
        float4 av1 = *reinterpret_cast<const float4*>(&A[(row0 + la_r) * H3DIM + k0 + 16 + la_k]);
        float4 bv0, bv1;
        if (full) {
            bv0 = *reinterpret_cast<const float4*>(&B[(k0 + lb_k) * D4 + col0 + lb_n]);
            bv1 = *reinterpret_cast<const float4*>(&B[(k0 + 16 + lb_k) * D4 + col0 + lb_n]);
        } else {
            float t0[4], t1[4];
#pragma unroll
            for (int j = 0; j < 4; j++) {
                int col = col0 + lb_n + j;
                t0[j] = (col < D4) ? B[(k0 + lb_k) * D4 + col] : 0.f;
                t1[j] = (col < D4) ? B[(k0 + 16 + lb_k) * D4 + col] : 0.f;
            }
            bv0 = make_float4(t0[0], t0[1], t0[2], t0[3]);
            bv1 = make_float4(t1[0], t1[1], t1[2], t1[3]);
        }
        __syncthreads();
        As[la_k + 0][la_r] = av0.x;
        As[la_k + 1][la_r] = av0.y;
        As[la_k + 2][la_r] = av0.z;
        As[la_k + 3][la_r] = av0.w;
        As[la_k + 16][la_r] = av1.x;
        As[la_k + 17][la_r] = av1.y;
        As[la_k + 18][la_r] = av1.z;
        As[la_k + 19][la_r] = av1.w;
        *reinterpret_cast<float4*>(&Bs[lb_k][lb_n])      = bv0;
        *reinterpret_cast<float4*>(&Bs[lb_k + 16][lb_n]) = bv1;
        __syncthreads();
#pragma unroll
        for (int kk = 0; kk < 32; kk++) {
            float4 a4 = *reinterpret_cast<const float4*>(&As[kk][ty * 4]);
            float4 b4 = *reinterpret_cast<const float4*>(&Bs[kk][tx * 4]);
            float a[4] = {a4.x, a4.y, a4.z, a4.w};
            float b[4] = {b4.x, b4.y, b4.z, b4.w};
#pragma unroll
            for (int i = 0; i < 4; i++)
#pragma unroll
                for (int j = 0; j < 4; j++)
                    acc[i][j] += a[i] * b[j];
        }
    }
#pragma unroll
    for (int i = 0; i < 4; i++) {
        int row = row0 + ty * 4 + i;
#pragma unroll
        for (int j = 0; j < 4; j++) {
            int col = col0 + tx * 4 + j;
            if (col < D4) D[row * D4 + col] = acc[i][j] + bias[col];
        }
    }
}

// ---------------- scores: softmax(H1 @ w2 + b2), store fg probs class-major ----------------
__global__ __launch_bounds__(128) void scores_softmax_kernel(
    const float* __restrict__ H1, const float* __restrict__ w2,
    const float* __restrict__ b2, float* __restrict__ probs)
{
    const int r = blockIdx.x;
    const int t = threadIdx.x;
    __shared__ float h[H1DIM];
    __shared__ float lg[CC];
    __shared__ float red[128];

    h[t]       = H1[r * H1DIM + t];
    h[t + 128] = H1[r * H1DIM + t + 128];
    __syncthreads();

    if (t < CC) {
        float acc = b2[t];
        for (int k = 0; k < H1DIM; k++) acc += h[k] * w2[k * CC + t];
        lg[t] = acc;
    }
    __syncthreads();

    red[t] = (t < CC) ? lg[t] : -1e30f;
    __syncthreads();
    for (int s = 64; s > 0; s >>= 1) {
        if (t < s) red[t] = fmaxf(red[t], red[t + s]);
        __syncthreads();
    }
    float mx = red[0];
    __syncthreads();

    float e = 0.f;
    if (t < CC) e = expf(lg[t] - mx);
    red[t] = e;
    __syncthreads();
    for (int s = 64; s > 0; s >>= 1) {
        if (t < s) red[t] += red[t + s];
        __syncthreads();
    }
    float sum = red[0];

    if (t >= 1 && t < CC) probs[(t - 1) * NR + r] = e / sum;
}

// ---------------- per-class: compact -> rank -> thread-per-entry decode -> chunk64 ballot NMS
__global__ __launch_bounds__(512) void class_nms_kernel(
    const float* __restrict__ probs, const float* __restrict__ D,
    const float* __restrict__ rois, const float* __restrict__ im_info,
    float* __restrict__ out)
{
    const int c = blockIdx.x;          // fg class (real class c+1)
    const int t = threadIdx.x;
    const int lane = t & 63;
    const int wave = t >> 6;           // 0..7

    __shared__ float imv[3];
    __shared__ float cs_sc[NR];
    __shared__ int   cs_ix[NR];
    __shared__ float ss[NR];
    __shared__ int   sx[NR];
    __shared__ float bx[NR][4];
    __shared__ unsigned long long over64[64];
    __shared__ unsigned long long presup_w;
    __shared__ unsigned long long keep_w[16];
    __shared__ int vcount;

    if (t < 3) imv[t] = im_info[t];
    if (t < 16) keep_w[t] = 0ULL;
    if (t == 0) { vcount = 0; presup_w = 0ULL; }
    __syncthreads();

    // compact valid entries (order nondeterministic; rank restores determinism)
    for (int i = t; i < NR; i += 512) {
        float s = probs[c * NR + i];
        if (s > 0.05f) {
            int p = atomicAdd(&vcount, 1);
            cs_sc[p] = s; cs_ix[p] = i;
        }
    }
    __syncthreads();
    const int V = vcount;

    // wave-parallel exact stable rank (score desc, idx asc)
    for (int e = wave; e < V; e += 8) {
        const float se = cs_sc[e];
        const int   ie = cs_ix[e];
        int cnt = 0;
        for (int f = lane; f < V; f += 64) {
            float sf = cs_sc[f];
            int   jf = cs_ix[f];
            if (sf > se || (sf == se && jf < ie)) cnt++;
        }
#pragma unroll
        for (int off = 32; off; off >>= 1) cnt += __shfl_xor(cnt, off, 64);
        if (lane == 0) { ss[cnt] = se; sx[cnt] = ie; }
    }
    __syncthreads();

    // decode: one THREAD per sorted valid entry (4 deltas via one float4 from D)
    const float Hm1 = imv[0] - 1.f, Wm1 = imv[1] - 1.f, inv = 1.f / imv[2];
    for (int i = t; i < V; i += 512) {
        const int r = sx[i];
        float4 dd = *reinterpret_cast<const float4*>(&D[r * D4 + (c + 1) * 4]);
        float dx = dd.x * 0.1f, dy = dd.y * 0.1f;
        float dw = dd.z * 0.2f, dh = dd.w * 0.2f;
        float x1 = rois[r * 5 + 1], y1 = rois[r * 5 + 2];
        float x2 = rois[r * 5 + 3], y2 = rois[r * 5 + 4];
        float wdt = x2 - x1 + 1.f, hgt = y2 - y1 + 1.f;
        float ctx = x1 + 0.5f * wdt, cty = y1 + 0.5f * hgt;
        float pcx = dx * wdt + ctx, pcy = dy * hgt + cty;
        float pw = expf(dw) * wdt, ph = expf(dh) * hgt;
        bx[i][0] = fminf(fmaxf(pcx - 0.5f * pw, 0.f), Wm1) * inv;
        bx[i][1] = fminf(fmaxf(pcy - 0.5f * ph, 0.f), Hm1) * inv;
        bx[i][2] = fminf(fmaxf(pcx + 0.5f * pw, 0.f), Wm1) * inv;
        bx[i][3] = fminf(fmaxf(pcy + 0.5f * ph, 0.f), Hm1) * inv;
    }
    __syncthreads();

    // NMS in 64-chunks: parallel ballot matrix + register-resident wave-0 scan
    for (int cs = 0; cs < V; cs += 64) {
        const int n = min(64, V - cs);

        for (int i = wave; i < n; i += 8) {
            const int gi = cs + i;
            const float x1i = bx[gi][0], y1i = bx[gi][1], x2i = bx[gi][2], y2i = bx[gi][3];
            const float ai = (x2i - x1i + 1.f) * (y2i - y1i + 1.f);

            // cross-chunk presup vs kept boxes of earlier chunks
            if (cs > 0) {
                int sup = 0;
                for (int j = lane; j < cs; j += 64) {
                    if ((keep_w[j >> 6] >> (j & 63)) & 1ULL) {
                        float iw = fminf(x2i, bx[j][2]) - fmaxf(x1i, bx[j][0]) + 1.f;
                        float ih = fminf(y2i, bx[j][3]) - fmaxf(y1i, bx[j][1]) + 1.f;
                        if (iw > 0.f && ih > 0.f) {
                            float inter = iw * ih;
                            float aj = (bx[j][2] - bx[j][0] + 1.f) * (bx[j][3] - bx[j][1] + 1.f);
                            if (inter / (ai + aj - inter) > 0.3f) sup = 1;
                        }
                    }
                }
                int anysup = __any(sup);
                if (anysup && lane == 0) atomicOr(&presup_w, 1ULL << i);
            }

            // symmetric intra-chunk overlap row (self bit set -> self-clearing scan)
            int pred = 0;
            if (lane < n) {
                const int gj = cs + lane;
                float iw = fminf(x2i, bx[gj][2]) - fmaxf(x1i, bx[gj][0]) + 1.f;
                float ih = fminf(y2i, bx[gj][3]) - fmaxf(y1i, bx[gj][1]) + 1.f;
                if (iw > 0.f && ih > 0.f) {
                    float inter = iw * ih;
                    float aj = (bx[gj][2] - bx[gj][0] + 1.f) * (bx[gj][3] - bx[gj][1] + 1.f);
                    if (inter / (ai + aj - inter) > 0.3f) pred = 1;
                }
            }
            unsigned long long bits = __ballot(pred);
            if (lane == 0) over64[i] = bits;
        }
        __syncthreads();

        // wave-0 scan: rows in registers, leader via ballot+ctz, row fetch via shfl
        if (wave == 0) {
            unsigned long long row = over64[lane];
            bool alive = (lane < n) && !((presup_w >> lane) & 1ULL);
            bool mykeep = false;
            while (true) {
                unsigned long long am = __ballot(alive ? 1 : 0);
                if (am == 0ULL) break;
                int ldr = __builtin_ctzll(am);
                unsigned long long rowL = __shfl(row, ldr, 64);
                if (lane == ldr) mykeep = true;
                if ((rowL >> lane) & 1ULL) alive = false;   // leader clears itself too
            }
            unsigned long long km = __ballot(mykeep ? 1 : 0);
            if (lane == 0) { keep_w[cs >> 6] = km; presup_w = 0ULL; }
        }
        __syncthreads();
    }

    // emit dets[c][i][6]
    for (int i = t; i < NR; i += 512) {
        float2* o = reinterpret_cast<float2*>(&out[(size_t)(c * NR + i) * 6]);
        bool kp = (i < V) && ((keep_w[i >> 6] >> (i & 63)) & 1ULL);
        float2 p0, p1, p2;
        if (kp) {
            p0 = make_float2(bx[i][0], bx[i][1]);
            p1 = make_float2(bx[i][2], bx[i][3]);
            p2 = make_float2(ss[i], (float)c);
        } else {
            p0 = make_float2(0.f, 0.f);
            p1 = make_float2(0.f, 0.f);
            p2 = make_float2(0.f, 0.f);
        }
        o[0] = p0; o[1] = p1; o[2] = p2;
    }
}

extern "C" void kernel_launch(void* const* d_in, const int* in_sizes, int n_in,
                              void* d_out, int out_size, void* d_ws, size_t ws_size,
                              hipStream_t stream)
{
    const float* X    = (const float*)d_in[0];
    const float* rois = (const float*)d_in[1];
    const float* imi  = (const float*)d_in[2];
    const float* w1   = (const float*)d_in[3];
    const float* b1   = (const float*)d_in[4];
    const float* w2   = (const float*)d_in[5];
    const float* b2   = (const float*)d_in[6];
    const float* w3   = (const float*)d_in[7];
    const float* b3   = (const float*)d_in[8];
    const float* w4   = (const float*)d_in[9];
    const float* b4   = (const float*)d_in[10];
    float* out = (float*)d_out;

    float* ws    = (float*)d_ws;
    float* H1    = ws;                       // 1024*256
    float* H3    = H1 + NR * H1DIM;          // 1024*512
    float* probs = H3 + NR * H3DIM;          // 80*1024
    float* D     = probs + NFG * NR;         // 1024*324

    gemm2_relu_kernel<<<dim3(12, NR / 64), 256, 0, stream>>>(X, w1, b1, H1, w3, b3, H3);
    gemm_deltas_kernel<<<dim3(6, NR / 64), 256, 0, stream>>>(H3, w4, b4, D);
    scores_softmax_kernel<<<NR, 128, 0, stream>>>(H1, w2, b2, probs);
    class_nms_kernel<<<NFG, 512, 0, stream>>>(probs, D, rois, imi, out);
}

// Round 9
// 212.385 us; speedup vs baseline: 1.3341x; 1.0951x over previous
//
#include <hip/hip_runtime.h>

#define NR 1024        // num rois
#define NFG 80         // fg classes
#define CC 81          // total classes
#define KDIM 2048
#define H1DIM 256
#define H3DIM 512
#define D4 324         // 4*81
#define NCOMB 768      // 256 + 512 combined output cols
#define SKM 4          // split-K for main GEMM (K=2048 -> 512/chunk)
#define SKD 8          // split-K for deltas GEMM (K=512 -> 64/chunk)

// ---------------- main GEMM partials: P[ks][1024][768] = X @ [w1|w3] (K-chunk ks) ----------
// 1-wave blocks, 64x64 tile, 8x8 microtile (ratio 1 FMA/LDS-byte), grid 12x16x4 = 768 blocks.
__global__ __launch_bounds__(64) void gemm_main_kernel(
    const float* __restrict__ X, const float* __restrict__ w1,
    const float* __restrict__ w3, float* __restrict__ P)
{
    const int nb = blockIdx.x;             // 0..11 combined col-tile
    const int mb = blockIdx.y;             // 0..15
    const int ks = blockIdx.z;             // 0..3
    const float* B; int Ncols, colbase;
    if (nb < 4) { B = w1; Ncols = H1DIM; colbase = nb * 64; }
    else        { B = w3; Ncols = H3DIM; colbase = (nb - 4) * 64; }
    const int row0 = mb * 64;
    const int kend = ks * 512 + 512;

    __shared__ float As[32][64];   // [k][m]
    __shared__ float Bs[32][64];   // [k][n]
    const int t = threadIdx.x;
    const int tx = t & 7;          // 8 col-groups
    const int ty = t >> 3;         // 8 row-groups

    float acc[8][8] = {};

    for (int k0 = ks * 512; k0 < kend; k0 += 32) {
        float4 a[8], b[8];
#pragma unroll
        for (int j = 0; j < 8; j++)
            a[j] = *reinterpret_cast<const float4*>(&X[(row0 + t) * KDIM + k0 + j * 4]);
#pragma unroll
        for (int j = 0; j < 8; j++)
            b[j] = *reinterpret_cast<const float4*>(
                &B[(k0 + (t >> 4) + j * 4) * Ncols + colbase + (t & 15) * 4]);
        __syncthreads();
#pragma unroll
        for (int j = 0; j < 8; j++) {
            As[j * 4 + 0][t] = a[j].x;
            As[j * 4 + 1][t] = a[j].y;
            As[j * 4 + 2][t] = a[j].z;
            As[j * 4 + 3][t] = a[j].w;
            *reinterpret_cast<float4*>(&Bs[(t >> 4) + j * 4][(t & 15) * 4]) = b[j];
        }
        __syncthreads();
#pragma unroll 8
        for (int kk = 0; kk < 32; kk++) {
            float4 a0 = *reinterpret_cast<const float4*>(&As[kk][ty * 8]);
            float4 a1 = *reinterpret_cast<const float4*>(&As[kk][ty * 8 + 4]);
            float4 b0 = *reinterpret_cast<const float4*>(&Bs[kk][tx * 8]);
            float4 b1 = *reinterpret_cast<const float4*>(&Bs[kk][tx * 8 + 4]);
            float av[8] = {a0.x, a0.y, a0.z, a0.w, a1.x, a1.y, a1.z, a1.w};
            float bv[8] = {b0.x, b0.y, b0.z, b0.w, b1.x, b1.y, b1.z, b1.w};
#pragma unroll
            for (int i = 0; i < 8; i++)
#pragma unroll
                for (int j = 0; j < 8; j++)
                    acc[i][j] += av[i] * bv[j];
        }
    }

    const int ccol = nb * 64 + tx * 8;     // combined col 0..767
#pragma unroll
    for (int i = 0; i < 8; i++) {
        const int row = row0 + ty * 8 + i;
        float* pr = &P[((size_t)ks * NR + row) * NCOMB + ccol];
        *reinterpret_cast<float4*>(&pr[0]) = make_float4(acc[i][0], acc[i][1], acc[i][2], acc[i][3]);
        *reinterpret_cast<float4*>(&pr[4]) = make_float4(acc[i][4], acc[i][5], acc[i][6], acc[i][7]);
    }
}

// ---------------- reduce: H1/H3 = relu(sum_ks P + bias) ----------------
__global__ __launch_bounds__(256) void reduce_main_kernel(
    const float* __restrict__ P, const float* __restrict__ b1,
    const float* __restrict__ b3, float* __restrict__ H1, float* __restrict__ H3)
{
    const int idx = blockIdx.x * 256 + threadIdx.x;        // float4 id
    if (idx >= NR * NCOMB / 4) return;
    const int row = idx / (NCOMB / 4);
    const int col = (idx % (NCOMB / 4)) * 4;
    const size_t off = (size_t)row * NCOMB + col;
    float4 s = *reinterpret_cast<const float4*>(&P[off]);
#pragma unroll
    for (int ksplit = 1; ksplit < SKM; ksplit++) {
        float4 p = *reinterpret_cast<const float4*>(&P[(size_t)ksplit * NR * NCOMB + off]);
        s.x += p.x; s.y += p.y; s.z += p.z; s.w += p.w;
    }
    float4 bb;
    if (col < H1DIM) bb = *reinterpret_cast<const float4*>(&b1[col]);
    else             bb = *reinterpret_cast<const float4*>(&b3[col - H1DIM]);
    s.x = fmaxf(s.x + bb.x, 0.f); s.y = fmaxf(s.y + bb.y, 0.f);
    s.z = fmaxf(s.z + bb.z, 0.f); s.w = fmaxf(s.w + bb.w, 0.f);
    if (col < H1DIM) *reinterpret_cast<float4*>(&H1[row * H1DIM + col]) = s;
    else             *reinterpret_cast<float4*>(&H3[row * H3DIM + col - H1DIM]) = s;
}

// ---------------- deltas GEMM partials: Pd[ks][1024][324] = H3 @ w4 (K-chunk ks) ------------
__global__ __launch_bounds__(64) void gemm_delta_kernel(
    const float* __restrict__ H3, const float* __restrict__ w4, float* __restrict__ Pd)
{
    const int nb = blockIdx.x;             // 0..5 (cols nb*64, last tile partial)
    const int mb = blockIdx.y;             // 0..15
    const int ks = blockIdx.z;             // 0..7
    const int colbase = nb * 64;
    const int row0 = mb * 64;
    const int kend = ks * 64 + 64;

    __shared__ float As[32][64];
    __shared__ float Bs[32][64];
    const int t = threadIdx.x;
    const int tx = t & 7;
    const int ty = t >> 3;

    float acc[8][8] = {};

    for (int k0 = ks * 64; k0 < kend; k0 += 32) {
        float4 a[8], b[8];
#pragma unroll
        for (int j = 0; j < 8; j++)
            a[j] = *reinterpret_cast<const float4*>(&H3[(row0 + t) * H3DIM + k0 + j * 4]);
        const int bcol = colbase + (t & 15) * 4;
        const bool bok = (bcol + 4 <= D4);
#pragma unroll
        for (int j = 0; j < 8; j++) {
            if (bok) b[j] = *reinterpret_cast<const float4*>(
                &w4[(k0 + (t >> 4) + j * 4) * D4 + bcol]);
            else     b[j] = make_float4(0.f, 0.f, 0.f, 0.f);
        }
        __syncthreads();
#pragma unroll
        for (int j = 0; j < 8; j++) {
            As[j * 4 + 0][t] = a[j].x;
            As[j * 4 + 1][t] = a[j].y;
            As[j * 4 + 2][t] = a[j].z;
            As[j * 4 + 3][t] = a[j].w;
            *reinterpret_cast<float4*>(&Bs[(t >> 4) + j * 4][(t & 15) * 4]) = b[j];
        }
        __syncthreads();
#pragma unroll 8
        for (int kk = 0; kk < 32; kk++) {
            float4 a0 = *reinterpret_cast<const float4*>(&As[kk][ty * 8]);
            float4 a1 = *reinterpret_cast<const float4*>(&As[kk][ty * 8 + 4]);
            float4 b0 = *reinterpret_cast<const float4*>(&Bs[kk][tx * 8]);
            float4 b1 = *reinterpret_cast<const float4*>(&Bs[kk][tx * 8 + 4]);
            float av[8] = {a0.x, a0.y, a0.z, a0.w, a1.x, a1.y, a1.z, a1.w};
            float bv[8] = {b0.x, b0.y, b0.z, b0.w, b1.x, b1.y, b1.z, b1.w};
#pragma unroll
            for (int i = 0; i < 8; i++)
#pragma unroll
                for (int j = 0; j < 8; j++)
                    acc[i][j] += av[i] * bv[j];
        }
    }

    const int pcol0 = colbase + tx * 8;
#pragma unroll
    for (int i = 0; i < 8; i++) {
        const int row = row0 + ty * 8 + i;
        float* pr = &Pd[((size_t)ks * NR + row) * D4 + pcol0];
        if (pcol0 + 4 <= D4)
            *reinterpret_cast<float4*>(&pr[0]) = make_float4(acc[i][0], acc[i][1], acc[i][2], acc[i][3]);
        if (pcol0 + 8 <= D4)
            *reinterpret_cast<float4*>(&pr[4]) = make_float4(acc[i][4], acc[i][5], acc[i][6], acc[i][7]);
    }
}

// ---------------- reduce: D = sum_ks Pd + b4 ----------------
__global__ __launch_bounds__(256) void reduce_delta_kernel(
    const float* __restrict__ Pd, const float* __restrict__ b4, float* __restrict__ D)
{
    const int idx = blockIdx.x * 256 + threadIdx.x;
    if (idx >= NR * D4 / 4) return;
    const int row = idx / (D4 / 4);
    const int col = (idx % (D4 / 4)) * 4;
    const size_t off = (size_t)row * D4 + col;
    float4 s = *reinterpret_cast<const float4*>(&Pd[off]);
#pragma unroll
    for (int ksplit = 1; ksplit < SKD; ksplit++) {
        float4 p = *reinterpret_cast<const float4*>(&Pd[(size_t)ksplit * NR * D4 + off]);
        s.x += p.x; s.y += p.y; s.z += p.z; s.w += p.w;
    }
    float4 bb = *reinterpret_cast<const float4*>(&b4[col]);
    s.x += bb.x; s.y += bb.y; s.z += bb.z; s.w += bb.w;
    *reinterpret_cast<float4*>(&D[off]) = s;
}

// ---------------- scores: softmax(H1 @ w2 + b2), store fg probs class-major ----------------
__global__ __launch_bounds__(128) void scores_softmax_kernel(
    const float* __restrict__ H1, const float* __restrict__ w2,
    const float* __restrict__ b2, float* __restrict__ probs)
{
    const int r = blockIdx.x;
    const int t = threadIdx.x;
    __shared__ float h[H1DIM];
    __shared__ float lg[CC];
    __shared__ float red[128];

    h[t]       = H1[r * H1DIM + t];
    h[t + 128] = H1[r * H1DIM + t + 128];
    __syncthreads();

    if (t < CC) {
        float acc = b2[t];
        for (int k = 0; k < H1DIM; k++) acc += h[k] * w2[k * CC + t];
        lg[t] = acc;
    }
    __syncthreads();

    red[t] = (t < CC) ? lg[t] : -1e30f;
    __syncthreads();
    for (int s = 64; s > 0; s >>= 1) {
        if (t < s) red[t] = fmaxf(red[t], red[t + s]);
        __syncthreads();
    }
    float mx = red[0];
    __syncthreads();

    float e = 0.f;
    if (t < CC) e = expf(lg[t] - mx);
    red[t] = e;
    __syncthreads();
    for (int s = 64; s > 0; s >>= 1) {
        if (t < s) red[t] += red[t + s];
        __syncthreads();
    }
    float sum = red[0];

    if (t >= 1 && t < CC) probs[(t - 1) * NR + r] = e / sum;
}

// ---------------- per-class: compact -> rank -> decode -> chunk64 ballot NMS ----------------
__global__ __launch_bounds__(512) void class_nms_kernel(
    const float* __restrict__ probs, const float* __restrict__ D,
    const float* __restrict__ rois, const float* __restrict__ im_info,
    float* __restrict__ out)
{
    const int c = blockIdx.x;
    const int t = threadIdx.x;
    const int lane = t & 63;
    const int wave = t >> 6;

    __shared__ float imv[3];
    __shared__ float cs_sc[NR];
    __shared__ int   cs_ix[NR];
    __shared__ float ss[NR];
    __shared__ int   sx[NR];
    __shared__ float bx[NR][4];
    __shared__ unsigned long long over64[64];
    __shared__ unsigned long long presup_w;
    __shared__ unsigned long long keep_w[16];
    __shared__ int vcount;

    if (t < 3) imv[t] = im_info[t];
    if (t < 16) keep_w[t] = 0ULL;
    if (t == 0) { vcount = 0; presup_w = 0ULL; }
    __syncthreads();

    for (int i = t; i < NR; i += 512) {
        float s = probs[c * NR + i];
        if (s > 0.05f) {
            int p = atomicAdd(&vcount, 1);
            cs_sc[p] = s; cs_ix[p] = i;
        }
    }
    __syncthreads();
    const int V = vcount;

    for (int e = wave; e < V; e += 8) {
        const float se = cs_sc[e];
        const int   ie = cs_ix[e];
        int cnt = 0;
        for (int f = lane; f < V; f += 64) {
            float sf = cs_sc[f];
            int   jf = cs_ix[f];
            if (sf > se || (sf == se && jf < ie)) cnt++;
        }
#pragma unroll
        for (int off = 32; off; off >>= 1) cnt += __shfl_xor(cnt, off, 64);
        if (lane == 0) { ss[cnt] = se; sx[cnt] = ie; }
    }
    __syncthreads();

    const float Hm1 = imv[0] - 1.f, Wm1 = imv[1] - 1.f, inv = 1.f / imv[2];
    for (int i = t; i < V; i += 512) {
        const int r = sx[i];
        float4 dd = *reinterpret_cast<const float4*>(&D[r * D4 + (c + 1) * 4]);
        float dx = dd.x * 0.1f, dy = dd.y * 0.1f;
        float dw = dd.z * 0.2f, dh = dd.w * 0.2f;
        float x1 = rois[r * 5 + 1], y1 = rois[r * 5 + 2];
        float x2 = rois[r * 5 + 3], y2 = rois[r * 5 + 4];
        float wdt = x2 - x1 + 1.f, hgt = y2 - y1 + 1.f;
        float ctx = x1 + 0.5f * wdt, cty = y1 + 0.5f * hgt;
        float pcx = dx * wdt + ctx, pcy = dy * hgt + cty;
        float pw = expf(dw) * wdt, ph = expf(dh) * hgt;
        bx[i][0] = fminf(fmaxf(pcx - 0.5f * pw, 0.f), Wm1) * inv;
        bx[i][1] = fminf(fmaxf(pcy - 0.5f * ph, 0.f), Hm1) * inv;
        bx[i][2] = fminf(fmaxf(pcx + 0.5f * pw, 0.f), Wm1) * inv;
        bx[i][3] = fminf(fmaxf(pcy + 0.5f * ph, 0.f), Hm1) * inv;
    }
    __syncthreads();

    for (int cs = 0; cs < V; cs += 64) {
        const int n = min(64, V - cs);

        for (int i = wave; i < n; i += 8) {
            const int gi = cs + i;
            const float x1i = bx[gi][0], y1i = bx[gi][1], x2i = bx[gi][2], y2i = bx[gi][3];
            const float ai = (x2i - x1i + 1.f) * (y2i - y1i + 1.f);

            if (cs > 0) {
                int sup = 0;
                for (int j = lane; j < cs; j += 64) {
                    if ((keep_w[j >> 6] >> (j & 63)) & 1ULL) {
                        float iw = fminf(x2i, bx[j][2]) - fmaxf(x1i, bx[j][0]) + 1.f;
                        float ih = fminf(y2i, bx[j][3]) - fmaxf(y1i, bx[j][1]) + 1.f;
                        if (iw > 0.f && ih > 0.f) {
                            float inter = iw * ih;
                            float aj = (bx[j][2] - bx[j][0] + 1.f) * (bx[j][3] - bx[j][1] + 1.f);
                            if (inter / (ai + aj - inter) > 0.3f) sup = 1;
                        }
                    }
                }
                int anysup = __any(sup);
                if (anysup && lane == 0) atomicOr(&presup_w, 1ULL << i);
            }

            int pred = 0;
            if (lane < n) {
                const int gj = cs + lane;
                float iw = fminf(x2i, bx[gj][2]) - fmaxf(x1i, bx[gj][0]) + 1.f;
                float ih = fminf(y2i, bx[gj][3]) - fmaxf(y1i, bx[gj][1]) + 1.f;
                if (iw > 0.f && ih > 0.f) {
                    float inter = iw * ih;
                    float aj = (bx[gj][2] - bx[gj][0] + 1.f) * (bx[gj][3] - bx[gj][1] + 1.f);
                    if (inter / (ai + aj - inter) > 0.3f) pred = 1;
                }
            }
            unsigned long long bits = __ballot(pred);
            if (lane == 0) over64[i] = bits;
        }
        __syncthreads();

        if (wave == 0) {
            unsigned long long row = over64[lane];
            bool alive = (lane < n) && !((presup_w >> lane) & 1ULL);
            bool mykeep = false;
            while (true) {
                unsigned long long am = __ballot(alive ? 1 : 0);
                if (am == 0ULL) break;
                int ldr = __builtin_ctzll(am);
                unsigned long long rowL = __shfl(row, ldr, 64);
                if (lane == ldr) mykeep = true;
                if ((rowL >> lane) & 1ULL) alive = false;
            }
            unsigned long long km = __ballot(mykeep ? 1 : 0);
            if (lane == 0) { keep_w[cs >> 6] = km; presup_w = 0ULL; }
        }
        __syncthreads();
    }

    for (int i = t; i < NR; i += 512) {
        float2* o = reinterpret_cast<float2*>(&out[(size_t)(c * NR + i) * 6]);
        bool kp = (i < V) && ((keep_w[i >> 6] >> (i & 63)) & 1ULL);
        float2 p0, p1, p2;
        if (kp) {
            p0 = make_float2(bx[i][0], bx[i][1]);
            p1 = make_float2(bx[i][2], bx[i][3]);
            p2 = make_float2(ss[i], (float)c);
        } else {
            p0 = make_float2(0.f, 0.f);
            p1 = make_float2(0.f, 0.f);
            p2 = make_float2(0.f, 0.f);
        }
        o[0] = p0; o[1] = p1; o[2] = p2;
    }
}

extern "C" void kernel_launch(void* const* d_in, const int* in_sizes, int n_in,
                              void* d_out, int out_size, void* d_ws, size_t ws_size,
                              hipStream_t stream)
{
    const float* X    = (const float*)d_in[0];
    const float* rois = (const float*)d_in[1];
    const float* imi  = (const float*)d_in[2];
    const float* w1   = (const float*)d_in[3];
    const float* b1   = (const float*)d_in[4];
    const float* w2   = (const float*)d_in[5];
    const float* b2   = (const float*)d_in[6];
    const float* w3   = (const float*)d_in[7];
    const float* b3   = (const float*)d_in[8];
    const float* w4   = (const float*)d_in[9];
    const float* b4   = (const float*)d_in[10];
    float* out = (float*)d_out;

    float* ws    = (float*)d_ws;
    float* H1    = ws;                         // 1024*256
    float* H3    = H1 + NR * H1DIM;            // 1024*512
    float* probs = H3 + NR * H3DIM;            // 80*1024
    float* D     = probs + NFG * NR;           // 1024*324
    float* P     = D + NR * D4;                // max(4*1024*768, 8*1024*324) floats (shared)

    gemm_main_kernel<<<dim3(12, 16, SKM), 64, 0, stream>>>(X, w1, w3, P);
    reduce_main_kernel<<<(NR * NCOMB / 4 + 255) / 256, 256, 0, stream>>>(P, b1, b3, H1, H3);
    scores_softmax_kernel<<<NR, 128, 0, stream>>>(H1, w2, b2, probs);
    gemm_delta_kernel<<<dim3(6, 16, SKD), 64, 0, stream>>>(H3, w4, P);
    reduce_delta_kernel<<<(NR * D4 / 4 + 255) / 256, 256, 0, stream>>>(P, b4, D);
    class_nms_kernel<<<NFG, 512, 0, stream>>>(probs, D, rois, imi, out);
}